// Round 5
// baseline (193.701 us; speedup 1.0000x reference)
//
#include <hip/hip_runtime.h>
#include <cmath>

#define BATCH 32768
#define SROW  66   // float2 stride per radix-8 row (padding breaks 8-way bank conflicts)

typedef float v2f __attribute__((ext_vector_type(2)));

__device__ __forceinline__ v2f mkc(float r, float i) { v2f t; t.x = r; t.y = i; return t; }
__device__ __forceinline__ v2f cmul(v2f a, v2f b) {
    v2f s = mkc(-a.y, a.x);
    return a * b.x + s * b.y;           // v_pk_mul + v_pk_fma
}
__device__ __forceinline__ v2f cmul_mi(v2f a){ return mkc(a.y, -a.x); }                  // a * (-i)
__device__ __forceinline__ v2f cmul_w81(v2f a){ const float C=0.70710678f; return mkc(C*(a.x+a.y), C*(a.y-a.x)); }
__device__ __forceinline__ v2f cmul_w83(v2f a){ const float C=0.70710678f; return mkc(C*(a.y-a.x), -C*(a.x+a.y)); }

// 8-point DFT, natural-order in/out (packed-fp32 complex adds)
__device__ __forceinline__ void dft8(v2f a[8]) {
    v2f t0=a[0]+a[4], t4=a[0]-a[4];
    v2f t1=a[1]+a[5], t5=a[1]-a[5];
    v2f t2=a[2]+a[6], t6=a[2]-a[6];
    v2f t3=a[3]+a[7], t7=a[3]-a[7];
    v2f u0=t0+t2, u2=t0-t2;
    v2f u1=t1+t3, u3=cmul_mi(t1-t3);
    a[0]=u0+u1; a[4]=u0-u1; a[2]=u2+u3; a[6]=u2-u3;
    v2f v0=t4, v1=cmul_w81(t5), v2=cmul_mi(t6), v3=cmul_w83(t7);
    v2f w0=v0+v2, w2=v0-v2;
    v2f w1=v1+v3, w3=cmul_mi(v1-v3);
    a[1]=w0+w1; a[5]=w0-w1; a[3]=w2+w3; a[7]=w2-w3;
}

// ---- DPP wave-64 reductions (pure VALU, no LDS pipe) ----
__device__ __forceinline__ float wave_sum64(float x) {
    x += __int_as_float(__builtin_amdgcn_update_dpp(0, __float_as_int(x), 0x111, 0xf, 0xf, true)); // row_shr:1
    x += __int_as_float(__builtin_amdgcn_update_dpp(0, __float_as_int(x), 0x112, 0xf, 0xf, true)); // row_shr:2
    x += __int_as_float(__builtin_amdgcn_update_dpp(0, __float_as_int(x), 0x114, 0xf, 0xf, true)); // row_shr:4
    x += __int_as_float(__builtin_amdgcn_update_dpp(0, __float_as_int(x), 0x118, 0xf, 0xf, true)); // row_shr:8
    x += __int_as_float(__builtin_amdgcn_update_dpp(0, __float_as_int(x), 0x142, 0xf, 0xf, true)); // row_bcast:15
    x += __int_as_float(__builtin_amdgcn_update_dpp(0, __float_as_int(x), 0x143, 0xf, 0xf, true)); // row_bcast:31
    return __int_as_float(__builtin_amdgcn_readlane(__float_as_int(x), 63));
}
// argmax with first-occurrence (min index) tie-break; result broadcast from lane 63
__device__ __forceinline__ int wave_argmax64(float best, int besti) {
#define AM_STEP(ctrl) { \
    float ob = __int_as_float(__builtin_amdgcn_update_dpp(__float_as_int(best), __float_as_int(best), ctrl, 0xf, 0xf, false)); \
    int   oi = __builtin_amdgcn_update_dpp(besti, besti, ctrl, 0xf, 0xf, false); \
    if (ob > best || (ob == best && oi < besti)) { best = ob; besti = oi; } }
    AM_STEP(0x111) AM_STEP(0x112) AM_STEP(0x114) AM_STEP(0x118) AM_STEP(0x142) AM_STEP(0x143)
#undef AM_STEP
    return __builtin_amdgcn_readlane(besti, 63);
}

// Replicates JAX fp32 argmin(|freq - target|), first-occurrence tie-break.
__device__ __forceinline__ int nearest_bin(float fs, float target) {
    float x = target * 1024.0f / fs;
    int i0 = (int)floorf(x);
    int lo = max(0, i0 - 1), hi = min(512, i0 + 2);
    int bi = lo; float bd = 1e30f;
    for (int i = lo; i <= hi; ++i) {
        float fr = (fs * 0.5f) * ((float)i / 512.0f);
        float d = fabsf(fr - target);
        if (d < bd) { bd = d; bi = i; }
    }
    return bi;
}

// 2 waves/block, 2 rows/wave. Per row: 512-pt complex FFT of packed even/odd
// samples (radix 8x8x8, register DFT-8s, two b64 LDS transposes), rfft combine
// via cross-lane shuffles, DPP reductions. No __syncthreads.
__global__ __launch_bounds__(128, 4) void fft_loss_kernel(
    const float* __restrict__ preds, const float* __restrict__ Fs,
    float* __restrict__ wavepartial)
{
    __shared__ v2f lds[2][2][8 * SROW];   // 16896 B

    const int tid  = threadIdx.x;
    const int wv   = tid >> 6;
    const int lane = tid & 63;
    const int row0 = blockIdx.x * 4 + wv * 2;

    v2f (*sm)[8 * SROW] = lds[wv];
    const v2f* x2 = reinterpret_cast<const v2f*>(preds) + (size_t)row0 * 512;

    // ---- Loads: both rows up front ----
    v2f z[2][8];
#pragma unroll
    for (int rr = 0; rr < 2; ++rr)
#pragma unroll
        for (int n1 = 0; n1 < 8; ++n1)
            z[rr][n1] = x2[rr * 512 + n1 * 64 + lane];

    // ---- Stage A: lane = n0; DFT8 over n1; twiddle W_512^{r*n0} (log-depth tree) ----
    {
        float sb, cb;
        __sincosf(-0.012271846f * (float)lane, &sb, &cb);   // -2pi/512 * lane
        v2f w1 = mkc(cb, sb);
        v2f w2 = cmul(w1, w1), w3 = cmul(w2, w1), w4 = cmul(w2, w2);
        v2f w5 = cmul(w3, w2), w6 = cmul(w3, w3), w7 = cmul(w4, w3);
#pragma unroll
        for (int rr = 0; rr < 2; ++rr) {
            dft8(z[rr]);
            z[rr][1]=cmul(z[rr][1],w1); z[rr][2]=cmul(z[rr][2],w2); z[rr][3]=cmul(z[rr][3],w3);
            z[rr][4]=cmul(z[rr][4],w4); z[rr][5]=cmul(z[rr][5],w5); z[rr][6]=cmul(z[rr][6],w6);
            z[rr][7]=cmul(z[rr][7],w7);
#pragma unroll
            for (int r = 0; r < 8; ++r) sm[rr][r * SROW + lane] = z[rr][r];
        }
    }

    // ---- Stage B: lane = (r, m0); DFT8 over m1; twiddle W_64^{s*m0} ----
    const int rB = lane & 7, m0 = lane >> 3;
    {
        float sb, cb;
        __sincosf(-0.09817477f * (float)m0, &sb, &cb);      // -2pi/64 * m0
        v2f b1 = mkc(cb, sb);
        v2f b2 = cmul(b1, b1), b3 = cmul(b2, b1), b4 = cmul(b2, b2);
        v2f b5 = cmul(b3, b2), b6 = cmul(b3, b3), b7 = cmul(b4, b3);
#pragma unroll
        for (int rr = 0; rr < 2; ++rr) {
#pragma unroll
            for (int m1 = 0; m1 < 8; ++m1) z[rr][m1] = sm[rr][rB * SROW + 8 * m1 + m0];
            dft8(z[rr]);
            z[rr][1]=cmul(z[rr][1],b1); z[rr][2]=cmul(z[rr][2],b2); z[rr][3]=cmul(z[rr][3],b3);
            z[rr][4]=cmul(z[rr][4],b4); z[rr][5]=cmul(z[rr][5],b5); z[rr][6]=cmul(z[rr][6],b6);
            z[rr][7]=cmul(z[rr][7],b7);
#pragma unroll
            for (int s = 0; s < 8; ++s)     // XOR-swizzled 8x8 transpose
                sm[rr][rB * SROW + 8 * m0 + ((s + m0) & 7)] = z[rr][s];
        }
    }

    // ---- Stage C: lane = (r, s); DFT8 over m0 -> z[rr][t] = Z[lane + 64 t] ----
    const int sC = lane >> 3;
#pragma unroll
    for (int rr = 0; rr < 2; ++rr) {
#pragma unroll
        for (int m = 0; m < 8; ++m) z[rr][m] = sm[rr][rB * SROW + 8 * m + ((sC + m) & 7)];
        dft8(z[rr]);
    }

    // ---- rfft combine: X[k] = E + W_1024^k * O; psd, sums, argmax ----
    const float fs_[2] = {Fs[row0], Fs[row0 + 1]};
    const int pl = (64 - lane) & 63;        // partner lane for k2 = (512-k)&511

    float wk0x, wk0y;
    {
        float sk, ck;
        __sincosf(-0.0061359233f * (float)lane, &sk, &ck);  // -2pi/1024 * lane
        wk0x = ck; wk0y = sk;
    }
    // W_16^t, t=0..7 (compile-time)
    const float WC[8] = {1.f, 0.92387953f, 0.70710678f, 0.38268343f, 0.f, -0.38268343f, -0.70710678f, -0.92387953f};
    const float WS[8] = {0.f, -0.38268343f, -0.70710678f, -0.92387953f, -1.f, -0.92387953f, -0.70710678f, -0.38268343f};

    float acc = 0.f;
    float psd[2][8];
#pragma unroll
    for (int rr = 0; rr < 2; ++rr) {
        const int left  = nearest_bin(fs_[rr], (float)(40.0 / 60.0));
        const int right = nearest_bin(fs_[rr], 3.0f);
        float total = 0.f, inb = 0.f, best = -1.f;
        int besti = 1 << 30;
#pragma unroll
        for (int t = 0; t < 8; ++t) {
            v2f a = z[rr][t];
            float px = __shfl(z[rr][7 - t].x, pl);
            float py = __shfl(z[rr][7 - t].y, pl);
            if (lane == 0) { px = z[rr][(8 - t) & 7].x; py = z[rr][(8 - t) & 7].y; }
            // independent per-t twiddle: wk = wk0 * W16^t
            float wkx = wk0x * WC[t] - wk0y * WS[t];
            float wky = wk0x * WS[t] + wk0y * WC[t];
            float ex = 0.5f * (a.x + px), ey = 0.5f * (a.y - py);
            float dx = a.x - px,          dy = a.y + py;
            float ox = 0.5f * dy,         oy = -0.5f * dx;
            float Xr = ex + wkx * ox - wky * oy;
            float Xi = ey + wkx * oy + wky * ox;
            float v  = Xr * Xr + Xi * Xi;
            psd[rr][t] = v;
            total += v;
            int k = lane + 64 * t;
            if (k >= left && k < right) {
                inb += v;
                if (v > best) { best = v; besti = k; }
            }
        }
        if (lane == 0) {    // Nyquist bin k=512 (never in band)
            float d = z[rr][0].x - z[rr][0].y;
            total += d * d;
        }

        total = wave_sum64(total);
        inb   = wave_sum64(inb);
        const int bbi = wave_argmax64(best, besti);

        int delta = (int)rintf(0.1f / ((fs_[rr] * 0.5f) / 513.0f));
        if (delta < 1) delta = 1;
        const int lo = max(left, bbi - delta), hi = min(right, bbi + delta);
        float wsum = 0.f;
#pragma unroll
        for (int t = 0; t < 8; ++t) {
            int k = lane + 64 * t;
            if (k >= lo && k < hi) wsum += psd[rr][t];
        }
        wsum = wave_sum64(wsum);

        float band = (total - inb) / (1e-8f + total);
        float den  = inb + 1e-8f * (float)(right - left);
        acc += band + (inb - wsum) / den;
    }

    if (lane == 0) wavepartial[blockIdx.x * 2 + wv] = acc;
}

__global__ __launch_bounds__(1024) void reduce_kernel(
    const float* __restrict__ wp, float* __restrict__ out)
{
    __shared__ float w[16];
    const int t = threadIdx.x;
    float acc = 0.f;
#pragma unroll
    for (int i = 0; i < 16; ++i) acc += wp[t + 1024 * i];
    acc = wave_sum64(acc);
    const int lane = t & 63, wvi = t >> 6;
    if (lane == 0) w[wvi] = acc;
    __syncthreads();
    if (t == 0) {
        float s = 0.f;
        for (int i = 0; i < 16; ++i) s += w[i];
        out[0] = s * (1.0f / (float)BATCH);
    }
}

extern "C" void kernel_launch(void* const* d_in, const int* in_sizes, int n_in,
                              void* d_out, int out_size, void* d_ws, size_t ws_size,
                              hipStream_t stream) {
    const float* preds = (const float*)d_in[0];
    const float* Fs    = (const float*)d_in[1];
    float* wp          = (float*)d_ws;      // 16384 floats = 64 KB
    float* out         = (float*)d_out;

    fft_loss_kernel<<<BATCH / 4, 128, 0, stream>>>(preds, Fs, wp);
    reduce_kernel<<<1, 1024, 0, stream>>>(wp, out);
}